// Round 1
// baseline (48.199 us; speedup 1.0000x reference)
//
#include <hip/hip_runtime.h>
#include <math.h>

// AM-Softmax loss: B=2048 rows, C=32000 cols, fp32 logits, int labels.
// loss = mean_b( logsumexp_j(z_bj) - num_b ),
//   z_bj = S*logit_bj (j != y_b), z_by = num_b = S*(logit_by - M).
// Computed in base-2 domain: z2 = (S*log2e)*logit, margin = S*M*log2e,
// per-row result = ln2 * (m2 + log2(sum 2^(z2-m2)) - num2).

#define B_ROWS 2048
#define C_COLS 32000
#define C4     (C_COLS / 4)   // 8000 float4 per row
#define BLOCK  256

__global__ __launch_bounds__(BLOCK) void amsm_row_kernel(
    const float* __restrict__ logits,
    const int*   __restrict__ labels,
    float*       __restrict__ row_out)
{
    const int   b   = blockIdx.x;
    const int   tid = threadIdx.x;
    const int   c   = labels[b];
    const float4* row = reinterpret_cast<const float4*>(logits + (size_t)b * C_COLS);

    const float K    = 30.0f * 1.44269504088896340736f;        // S * log2(e)
    const float MARG = 30.0f * 0.4f * 1.44269504088896340736f; // S*M * log2(e)

    float m   = -INFINITY;  // running max (base-2 domain)
    float s   = 0.0f;       // running sum of 2^(z-m)
    float num = -INFINITY;  // base-2 numerator (exactly one thread sets it)

    for (int j = tid; j < C4; j += BLOCK) {
        float4 v = row[j];
        float z0 = K * v.x, z1 = K * v.y, z2 = K * v.z, z3 = K * v.w;
        unsigned d = (unsigned)(c - (j << 2));
        if (d < 4u) {                       // this float4 holds the label col
            if      (d == 0u) { z0 -= MARG; num = z0; }
            else if (d == 1u) { z1 -= MARG; num = z1; }
            else if (d == 2u) { z2 -= MARG; num = z2; }
            else              { z3 -= MARG; num = z3; }
        }
        float vm = fmaxf(fmaxf(z0, z1), fmaxf(z2, z3));
        if (vm > m) {                       // rare after warm-up
            s *= exp2f(m - vm);             // exp2f(-inf)=0 handles first iter
            m  = vm;
        }
        s += exp2f(z0 - m) + exp2f(z1 - m) + exp2f(z2 - m) + exp2f(z3 - m);
    }

    // ---- wave-level merge of (m, s) pairs; max-merge of num ----
    #pragma unroll
    for (int off = 1; off < 64; off <<= 1) {
        float m2 = __shfl_xor(m, off);
        float s2 = __shfl_xor(s, off);
        float n2 = __shfl_xor(num, off);
        float M_ = fmaxf(m, m2);
        s   = s * exp2f(m - M_) + s2 * exp2f(m2 - M_);
        m   = M_;
        num = fmaxf(num, n2);
    }

    // ---- cross-wave merge (4 waves) ----
    __shared__ float sm[4], ss[4], sn[4];
    const int wave = tid >> 6, lane = tid & 63;
    if (lane == 0) { sm[wave] = m; ss[wave] = s; sn[wave] = num; }
    __syncthreads();
    if (tid == 0) {
        float M_ = fmaxf(fmaxf(sm[0], sm[1]), fmaxf(sm[2], sm[3]));
        float S_ = ss[0] * exp2f(sm[0] - M_) + ss[1] * exp2f(sm[1] - M_)
                 + ss[2] * exp2f(sm[2] - M_) + ss[3] * exp2f(sm[3] - M_);
        float n  = fmaxf(fmaxf(sn[0], sn[1]), fmaxf(sn[2], sn[3]));
        float lse2 = M_ + log2f(S_);
        row_out[b] = 0.69314718055994530942f * (lse2 - n);  // ln2 * (...)
    }
}

__global__ __launch_bounds__(BLOCK) void amsm_reduce_kernel(
    const float* __restrict__ row_out,
    float*       __restrict__ out)
{
    float acc = 0.0f;
    for (int i = threadIdx.x; i < B_ROWS; i += BLOCK) acc += row_out[i];
    #pragma unroll
    for (int off = 1; off < 64; off <<= 1) acc += __shfl_xor(acc, off);
    __shared__ float sh[4];
    const int wave = threadIdx.x >> 6;
    if ((threadIdx.x & 63) == 0) sh[wave] = acc;
    __syncthreads();
    if (threadIdx.x == 0)
        out[0] = (sh[0] + sh[1] + sh[2] + sh[3]) * (1.0f / (float)B_ROWS);
}

extern "C" void kernel_launch(void* const* d_in, const int* in_sizes, int n_in,
                              void* d_out, int out_size, void* d_ws, size_t ws_size,
                              hipStream_t stream)
{
    const float* logits = (const float*)d_in[0];
    const int*   labels = (const int*)d_in[1];
    float*       out    = (float*)d_out;
    float*       rowbuf = (float*)d_ws;   // needs B_ROWS*4 = 8 KiB of scratch

    amsm_row_kernel<<<B_ROWS, BLOCK, 0, stream>>>(logits, labels, rowbuf);
    amsm_reduce_kernel<<<1, BLOCK, 0, stream>>>(rowbuf, out);
}

// Round 3
// 47.402 us; speedup vs baseline: 1.0168x; 1.0168x over previous
//
#include <hip/hip_runtime.h>
#include <math.h>

// AM-Softmax loss: B=2048 rows, C=32000 cols, fp32 logits, int labels.
// loss = mean_b( logsumexp_j(z_bj) - num_b ),
//   z_bj = S*logit_bj (j != y_b), z_by = num_b = S*(logit_by - M).
// Base-2 domain: z2 = (S*log2e)*logit, margin2 = S*M*log2e.
// Label column handled OUTSIDE the streaming loop: loop sums unadjusted
// 2^(z-m) over all cols; at the end subtract the unadjusted label term
// and add the margin-adjusted one.

#define B_ROWS 2048
#define C_COLS 32000
#define BLOCK  256
#define FULL   31            // 31*256 = 7936 float4
#define TAILN  64            // 8000 - 7936, handled by threads 0..63

typedef __attribute__((ext_vector_type(4))) float f32x4;  // clang-native vector

__device__ __forceinline__ float ex2(float x) { return __builtin_amdgcn_exp2f(x); }

__global__ __launch_bounds__(BLOCK) void amsm_row_kernel(
    const float* __restrict__ logits,
    const int*   __restrict__ labels,
    float*       __restrict__ row_out)
{
    const int    b    = blockIdx.x;
    const int    tid  = threadIdx.x;
    const int    c    = labels[b];
    const size_t base = (size_t)b * C_COLS;
    const f32x4* row  = reinterpret_cast<const f32x4*>(logits + base);

    const float K    = 43.2808512266689022f;   // 30 * log2(e)
    const float MARG = 17.3123404906675609f;   // 30*0.4 * log2(e)

    const float zy = K * logits[base + c];     // broadcast load

    float m = -INFINITY;   // running max (base-2 domain)
    float s = 0.0f;        // running sum of 2^(z - m)

    #pragma unroll 4
    for (int k = 0; k < FULL; ++k) {
        f32x4 v = __builtin_nontemporal_load(row + tid + (k << 8));
        float z0 = K * v.x, z1 = K * v.y, z2 = K * v.z, z3 = K * v.w;
        float vm = fmaxf(fmaxf(z0, z1), fmaxf(z2, z3));
        if (vm > m) {                 // wave-rare after the first few iters
            s *= ex2(m - vm);         // exp2(-inf) = 0 covers the first iter
            m  = vm;
        }
        s += ex2(z0 - m) + ex2(z1 - m) + ex2(z2 - m) + ex2(z3 - m);
    }
    if (tid < TAILN) {                // tail: last 64 float4 of the row
        f32x4 v = __builtin_nontemporal_load(row + 7936 + tid);
        float z0 = K * v.x, z1 = K * v.y, z2 = K * v.z, z3 = K * v.w;
        float vm = fmaxf(fmaxf(z0, z1), fmaxf(z2, z3));
        if (vm > m) { s *= ex2(m - vm); m = vm; }
        s += ex2(z0 - m) + ex2(z1 - m) + ex2(z2 - m) + ex2(z3 - m);
    }

    // ---- wave-level merge of (m, s) ----
    #pragma unroll
    for (int off = 1; off < 64; off <<= 1) {
        float m2 = __shfl_xor(m, off);
        float s2 = __shfl_xor(s, off);
        float M_ = fmaxf(m, m2);
        s = s * ex2(m - M_) + s2 * ex2(m2 - M_);
        m = M_;
    }

    // ---- cross-wave merge (4 waves) + label correction ----
    __shared__ float sm[4], ss[4];
    const int wave = tid >> 6, lane = tid & 63;
    if (lane == 0) { sm[wave] = m; ss[wave] = s; }
    __syncthreads();
    if (tid == 0) {
        float M_ = fmaxf(fmaxf(sm[0], sm[1]), fmaxf(sm[2], sm[3]));
        float S_ = ss[0] * ex2(sm[0] - M_) + ss[1] * ex2(sm[1] - M_)
                 + ss[2] * ex2(sm[2] - M_) + ss[3] * ex2(sm[3] - M_);
        float num = zy - MARG;
        // swap in the margin-adjusted label term
        S_ = S_ - ex2(zy - M_) + ex2(num - M_);
        float lse2 = M_ + log2f(S_);
        row_out[b] = 0.69314718055994530942f * (lse2 - num);  // ln2 * (...)
    }
}

__global__ __launch_bounds__(BLOCK) void amsm_reduce_kernel(
    const float* __restrict__ row_out,
    float*       __restrict__ out)
{
    float acc = 0.0f;
    for (int i = threadIdx.x; i < B_ROWS; i += BLOCK) acc += row_out[i];
    #pragma unroll
    for (int off = 1; off < 64; off <<= 1) acc += __shfl_xor(acc, off);
    __shared__ float sh[4];
    const int wave = threadIdx.x >> 6;
    if ((threadIdx.x & 63) == 0) sh[wave] = acc;
    __syncthreads();
    if (threadIdx.x == 0)
        out[0] = (sh[0] + sh[1] + sh[2] + sh[3]) * (1.0f / (float)B_ROWS);
}

extern "C" void kernel_launch(void* const* d_in, const int* in_sizes, int n_in,
                              void* d_out, int out_size, void* d_ws, size_t ws_size,
                              hipStream_t stream)
{
    const float* logits = (const float*)d_in[0];
    const int*   labels = (const int*)d_in[1];
    float*       out    = (float*)d_out;
    float*       rowbuf = (float*)d_ws;   // B_ROWS*4 = 8 KiB of scratch

    amsm_row_kernel<<<B_ROWS, BLOCK, 0, stream>>>(logits, labels, rowbuf);
    amsm_reduce_kernel<<<1, BLOCK, 0, stream>>>(rowbuf, out);
}